// Round 1
// baseline (522.342 us; speedup 1.0000x reference)
//
#include <hip/hip_runtime.h>
#include <hip/hip_bf16.h>
#include <hip/hip_fp16.h>

#define B_ 32
#define T_ 2048
#define D_ 1024
#define U_ 1024
#define M_ (B_ * T_)   // 65536
#define NT_ 8          // U_/128 partial-logit slabs

typedef _Float16 f16x8 __attribute__((ext_vector_type(8)));
typedef float f32x4 __attribute__((ext_vector_type(4)));

__device__ __forceinline__ float fast_tanh(float x) {
    // clamp so exp stays finite; tanh saturates (in f32) past ~9.01 anyway
    float xc = fminf(fmaxf(x, -10.f), 10.f);
    float e = __expf(2.f * xc);
    return 1.f - 2.f / (e + 1.f);
}

// ---------------- W1 [D][U] f32 -> W1t [U][D] f16 ----------------
__global__ void transpose_cast_kernel(const float* __restrict__ W1,
                                      _Float16* __restrict__ W1t) {
    int u = blockIdx.x * 256 + threadIdx.x;   // grid.x = 4
    int d0 = blockIdx.y * 64;                 // grid.y = 16
    for (int j = 0; j < 64; ++j) {
        int d = d0 + j;
        W1t[(size_t)u * D_ + d] = (_Float16)W1[(size_t)d * U_ + u];
    }
}

// ---------------- ph[b][u] = hidden[b]·W2[:,u] + b2[u] + b1[u] ----------------
__global__ void proj_h_kernel(const float* __restrict__ hidden,
                              const float* __restrict__ W2,
                              const float* __restrict__ b1,
                              const float* __restrict__ b2,
                              float* __restrict__ ph) {
    int u = blockIdx.x * 256 + threadIdx.x;   // grid.x = 4
    int b = blockIdx.y;                       // grid.y = 32
    float acc = 0.f;
    for (int d = 0; d < D_; ++d)
        acc = fmaf(hidden[b * D_ + d], W2[(size_t)d * U_ + u], acc);
    ph[b * U_ + u] = acc + b1[u] + b2[u];
}

// ---------------- fused GEMM + tanh + dot(V) -> partial logits ----------------
#define BM 128
#define BN 128
#define BK 64

__global__ __launch_bounds__(256, 2)
void gemm_logits_kernel(const float* __restrict__ A,      // features [M][D] f32
                        const _Float16* __restrict__ Bt,  // W1t [U][D] f16
                        const float* __restrict__ ph,     // [B][U]
                        const float* __restrict__ V,      // [U]
                        float* __restrict__ part)         // [NT_][M]
{
    __shared__ _Float16 As[BM * BK];
    __shared__ _Float16 Bs[BN * BK];
    __shared__ float lbuf[2][BM];

    int bid = blockIdx.x;
    int nt = bid & 7;
    int mt = bid >> 3;
    int tid = threadIdx.x;
    int lane = tid & 63, wid = tid >> 6;
    int wr = wid >> 1, wc = wid & 1;
    int lrow = lane & 15, lk = (lane >> 4) << 3;

    const float* Ag = A + (size_t)(mt * BM) * D_;
    const _Float16* Bg = Bt + (size_t)(nt * BN) * D_;

    f32x4 acc[4][4] = {};

    int srow = tid >> 3;   // 0..31
    int soct = tid & 7;    // 0..7

    for (int k0 = 0; k0 < D_; k0 += BK) {
        // stage A (f32 -> f16), XOR-swizzled 16B units
        #pragma unroll
        for (int p = 0; p < 4; ++p) {
            int row = srow + p * 32;
            const float* g = Ag + (size_t)row * D_ + k0 + soct * 8;
            f32x4 v0 = *(const f32x4*)g;
            f32x4 v1 = *(const f32x4*)(g + 4);
            f16x8 h;
            h[0] = (_Float16)v0[0]; h[1] = (_Float16)v0[1];
            h[2] = (_Float16)v0[2]; h[3] = (_Float16)v0[3];
            h[4] = (_Float16)v1[0]; h[5] = (_Float16)v1[1];
            h[6] = (_Float16)v1[2]; h[7] = (_Float16)v1[3];
            int unit = soct ^ (row & 7);
            *(f16x8*)&As[row * BK + unit * 8] = h;
        }
        // stage B (already f16)
        #pragma unroll
        for (int p = 0; p < 4; ++p) {
            int row = srow + p * 32;
            f16x8 h = *(const f16x8*)(Bg + (size_t)row * D_ + k0 + soct * 8);
            int unit = soct ^ (row & 7);
            *(f16x8*)&Bs[row * BK + unit * 8] = h;
        }
        __syncthreads();
        #pragma unroll
        for (int kk = 0; kk < BK; kk += 32) {
            int k = kk + lk;
            f16x8 af[4], bf[4];
            #pragma unroll
            for (int m = 0; m < 4; ++m) {
                int row = wr * 64 + m * 16 + lrow;
                af[m] = *(const f16x8*)&As[row * BK + (((k >> 3) ^ (row & 7)) << 3)];
            }
            #pragma unroll
            for (int n = 0; n < 4; ++n) {
                int row = wc * 64 + n * 16 + lrow;
                bf[n] = *(const f16x8*)&Bs[row * BK + (((k >> 3) ^ (row & 7)) << 3)];
            }
            #pragma unroll
            for (int m = 0; m < 4; ++m)
                #pragma unroll
                for (int n = 0; n < 4; ++n)
                    acc[m][n] = __builtin_amdgcn_mfma_f32_16x16x32_f16(
                        af[m], bf[n], acc[m][n], 0, 0, 0);
        }
        __syncthreads();
    }

    // epilogue: s = tanh(acc + ph[b][u]); partial_logit[row] = sum_u s*V[u]
    int bidx = mt >> 4;   // 2048/128 = 16 m-tiles per batch
    const float* phb = ph + bidx * U_;
    float Vv[4], phv[4];
    #pragma unroll
    for (int n = 0; n < 4; ++n) {
        int u = nt * BN + wc * 64 + n * 16 + lrow;
        Vv[n] = V[u];
        phv[n] = phb[u];
    }
    #pragma unroll
    for (int m = 0; m < 4; ++m) {
        #pragma unroll
        for (int r = 0; r < 4; ++r) {
            float p = 0.f;
            #pragma unroll
            for (int n = 0; n < 4; ++n) {
                float s = fast_tanh(acc[m][n][r] + phv[n]);
                p = fmaf(s, Vv[n], p);
            }
            #pragma unroll
            for (int off = 1; off < 16; off <<= 1)
                p += __shfl_xor(p, off, 64);
            if (lrow == 0) {
                int row = wr * 64 + m * 16 + ((lane >> 4) << 2) + r;
                lbuf[wc][row] = p;
            }
        }
    }
    __syncthreads();
    if (tid < BM) {
        float v = lbuf[0][tid] + lbuf[1][tid];
        part[(size_t)nt * M_ + mt * BM + tid] = v;
    }
}

// ---------------- softmax over T per batch ----------------
__global__ void softmax_kernel(const float* __restrict__ part,
                               float* __restrict__ wout) {
    int b = blockIdx.x;     // 32
    int tid = threadIdx.x;  // 256
    __shared__ float red[8];
    float l[8];
    #pragma unroll
    for (int j = 0; j < 8; ++j) {
        int t = tid + j * 256;
        float s = 0.f;
        #pragma unroll
        for (int p = 0; p < NT_; ++p)
            s += part[(size_t)p * M_ + b * T_ + t];
        l[j] = s;
    }
    float mx = l[0];
    #pragma unroll
    for (int j = 1; j < 8; ++j) mx = fmaxf(mx, l[j]);
    #pragma unroll
    for (int off = 1; off < 64; off <<= 1) mx = fmaxf(mx, __shfl_xor(mx, off, 64));
    int wv = tid >> 6;
    if ((tid & 63) == 0) red[wv] = mx;
    __syncthreads();
    mx = fmaxf(fmaxf(red[0], red[1]), fmaxf(red[2], red[3]));
    float e[8];
    float sum = 0.f;
    #pragma unroll
    for (int j = 0; j < 8; ++j) { e[j] = __expf(l[j] - mx); sum += e[j]; }
    #pragma unroll
    for (int off = 1; off < 64; off <<= 1) sum += __shfl_xor(sum, off, 64);
    if ((tid & 63) == 0) red[4 + wv] = sum;
    __syncthreads();
    sum = red[4] + red[5] + red[6] + red[7];
    float inv = 1.f / sum;
    #pragma unroll
    for (int j = 0; j < 8; ++j)
        wout[b * T_ + tid + j * 256] = e[j] * inv;
}

// ---------------- context = sum_t w_t * features[b,t,:] ----------------
#define TCH 128   // 16 chunks over T
__global__ void context_partial_kernel(const float* __restrict__ feats,
                                       const float* __restrict__ w,
                                       float* __restrict__ cpart) {
    int b = blockIdx.x;    // 32
    int tc = blockIdx.y;   // 16
    int tid = threadIdx.x; // 256 -> 4 floats each
    f32x4 acc = {0.f, 0.f, 0.f, 0.f};
    const float* f = feats + ((size_t)b * T_ + tc * TCH) * D_ + tid * 4;
    const float* wp = w + b * T_ + tc * TCH;
    for (int t = 0; t < TCH; ++t) {
        float wt = wp[t];
        f32x4 fv = *(const f32x4*)(f + (size_t)t * D_);
        acc[0] = fmaf(wt, fv[0], acc[0]);
        acc[1] = fmaf(wt, fv[1], acc[1]);
        acc[2] = fmaf(wt, fv[2], acc[2]);
        acc[3] = fmaf(wt, fv[3], acc[3]);
    }
    *(f32x4*)&cpart[((size_t)tc * B_ + b) * D_ + tid * 4] = acc;
}

__global__ void context_reduce_kernel(const float* __restrict__ cpart,
                                      float* __restrict__ out) {
    int i = blockIdx.x * 256 + threadIdx.x;   // grid 128 -> 32768
    float s = 0.f;
    #pragma unroll
    for (int tc = 0; tc < 16; ++tc)
        s += cpart[(size_t)tc * (B_ * D_) + i];
    out[i] = s;
}

extern "C" void kernel_launch(void* const* d_in, const int* in_sizes, int n_in,
                              void* d_out, int out_size, void* d_ws, size_t ws_size,
                              hipStream_t stream) {
    const float* features = (const float*)d_in[0];
    const float* hidden   = (const float*)d_in[1];
    const float* W1       = (const float*)d_in[2];
    const float* b1       = (const float*)d_in[3];
    const float* W2       = (const float*)d_in[4];
    const float* b2       = (const float*)d_in[5];
    const float* V        = (const float*)d_in[6];
    // bV: softmax is shift-invariant; logits only feed softmax -> bV drops out.

    float* ctx_out = (float*)d_out;            // [B,D] = 32768
    float* w_out   = ctx_out + B_ * D_;        // [B,T,1] = 65536

    char* ws = (char*)d_ws;
    _Float16* W1t = (_Float16*)ws;                              // 2 MB
    float* ph     = (float*)(ws + (2 << 20));                   // 128 KB
    float* part   = (float*)(ws + (2 << 20) + (1 << 17));       // 2 MB
    float* cpart  = (float*)(ws + (4 << 20) + (1 << 17));       // 2 MB

    transpose_cast_kernel<<<dim3(4, 16), 256, 0, stream>>>(W1, W1t);
    proj_h_kernel<<<dim3(4, 32), 256, 0, stream>>>(hidden, W2, b1, b2, ph);
    gemm_logits_kernel<<<(M_ / BM) * (U_ / BN), 256, 0, stream>>>(features, W1t, ph, V, part);
    softmax_kernel<<<B_, 256, 0, stream>>>(part, w_out);
    context_partial_kernel<<<dim3(B_, 16), 256, 0, stream>>>(features, w_out, cpart);
    context_reduce_kernel<<<(B_ * D_) / 256, 256, 0, stream>>>(cpart, ctx_out);
}

// Round 2
// 346.100 us; speedup vs baseline: 1.5092x; 1.5092x over previous
//
#include <hip/hip_runtime.h>
#include <hip/hip_bf16.h>
#include <hip/hip_fp16.h>

#define B_ 32
#define T_ 2048
#define D_ 1024
#define U_ 1024
#define M_ (B_ * T_)   // 65536
#define NT_ 8          // U_/128 partial-logit slabs

typedef _Float16 f16x8 __attribute__((ext_vector_type(8)));
typedef _Float16 f16x4 __attribute__((ext_vector_type(4)));
typedef float f32x4 __attribute__((ext_vector_type(4)));

__device__ __forceinline__ float fast_tanh(float x) {
    float xc = fminf(fmaxf(x, -10.f), 10.f);
    float e = __expf(2.f * xc);
    return 1.f - 2.f / (e + 1.f);
}

__device__ __forceinline__ void load_lds16(const void* g, void* l) {
    __builtin_amdgcn_global_load_lds(
        (const __attribute__((address_space(1))) void*)g,
        (__attribute__((address_space(3))) void*)l, 16, 0, 0);
}

// ---------------- features f32 -> f16 (linear copy) ----------------
__global__ void precast_kernel(const float* __restrict__ in,
                               _Float16* __restrict__ out) {
    size_t i = (size_t)blockIdx.x * 256 + threadIdx.x;
    const size_t stride = (size_t)2048 * 256;
    const size_t n8 = (size_t)M_ * D_ / 8;
    for (size_t j = i; j < n8; j += stride) {
        f32x4 a = *(const f32x4*)(in + j * 8);
        f32x4 b = *(const f32x4*)(in + j * 8 + 4);
        f16x8 h;
        h[0] = (_Float16)a[0]; h[1] = (_Float16)a[1];
        h[2] = (_Float16)a[2]; h[3] = (_Float16)a[3];
        h[4] = (_Float16)b[0]; h[5] = (_Float16)b[1];
        h[6] = (_Float16)b[2]; h[7] = (_Float16)b[3];
        *(f16x8*)(out + j * 8) = h;
    }
}

// ---------------- W1 [D][U] f32 -> W1t [U][D] f16 ----------------
__global__ void transpose_cast_kernel(const float* __restrict__ W1,
                                      _Float16* __restrict__ W1t) {
    int u = blockIdx.x * 256 + threadIdx.x;   // grid.x = 4
    int d0 = blockIdx.y * 64;                 // grid.y = 16
    for (int j8 = 0; j8 < 8; ++j8) {
        f16x8 h;
        #pragma unroll
        for (int j = 0; j < 8; ++j)
            h[j] = (_Float16)W1[(size_t)(d0 + j8 * 8 + j) * U_ + u];
        *(f16x8*)&W1t[(size_t)u * D_ + d0 + j8 * 8] = h;
    }
}

// ---------------- ph[b][u] = hidden[b]·W2[:,u] + b2[u] + b1[u] ----------------
__global__ void proj_h_kernel(const float* __restrict__ hidden,
                              const float* __restrict__ W2,
                              const float* __restrict__ b1,
                              const float* __restrict__ b2,
                              float* __restrict__ ph) {
    int u = blockIdx.x * 256 + threadIdx.x;   // grid.x = 4
    int b = blockIdx.y;                       // grid.y = 32
    float acc = 0.f;
    for (int d = 0; d < D_; ++d)
        acc = fmaf(hidden[b * D_ + d], W2[(size_t)d * U_ + u], acc);
    ph[b * U_ + u] = acc + b1[u] + b2[u];
}

#define BM 128
#define BN 128
#define BK 64

// XCD-chunked block mapping: xcd = bid&7 owns mt in [xcd*64, xcd*64+64), all nt.
__device__ __forceinline__ void block_map(int bid, int& mt, int& nt) {
    int xcd = bid & 7;
    int local = bid >> 3;          // 0..511
    mt = xcd * 64 + (local >> 3);  // 0..511
    nt = local & 7;                // 0..7
}

// ---------------- fused GEMM(f16, global_load_lds) + tanh + dot(V) ----------------
__global__ __launch_bounds__(256, 3)
void gemm_logits_f16_kernel(const _Float16* __restrict__ A,   // featH [M][D]
                            const _Float16* __restrict__ Bt,  // W1t [U][D]
                            const float* __restrict__ ph,
                            const float* __restrict__ V,
                            float* __restrict__ part)
{
    __shared__ _Float16 As[BM * BK];   // 16 KB, linear (gload_lds constraint)
    __shared__ _Float16 Bs[BN * BK];   // 16 KB
    __shared__ float lbuf[2][BM];

    int mt, nt;
    block_map(blockIdx.x, mt, nt);

    int tid = threadIdx.x;
    int lane = tid & 63, wid = tid >> 6;
    int wr = wid >> 1, wc = wid & 1;
    int lrow = lane & 15, lk = (lane >> 4) << 3;

    const _Float16* Ag = A + (size_t)(mt * BM) * D_;
    const _Float16* Bg = Bt + (size_t)(nt * BN) * D_;

    f32x4 acc[4][4] = {};

    int srow = tid >> 3;        // 0..31
    int scol = (tid & 7) * 8;   // f16 elem offset within BK row

    for (int k0 = 0; k0 < D_; k0 += BK) {
        #pragma unroll
        for (int p = 0; p < 4; ++p) {
            int row = p * 32 + srow;
            load_lds16(Ag + (size_t)row * D_ + k0 + scol, &As[row * BK + scol]);
        }
        #pragma unroll
        for (int p = 0; p < 4; ++p) {
            int row = p * 32 + srow;
            load_lds16(Bg + (size_t)row * D_ + k0 + scol, &Bs[row * BK + scol]);
        }
        __syncthreads();
        #pragma unroll
        for (int kk = 0; kk < BK; kk += 32) {
            int k = kk + lk;
            f16x8 af[4], bf[4];
            #pragma unroll
            for (int m = 0; m < 4; ++m)
                af[m] = *(const f16x8*)&As[(wr * 64 + m * 16 + lrow) * BK + k];
            #pragma unroll
            for (int n = 0; n < 4; ++n)
                bf[n] = *(const f16x8*)&Bs[(wc * 64 + n * 16 + lrow) * BK + k];
            #pragma unroll
            for (int m = 0; m < 4; ++m)
                #pragma unroll
                for (int n = 0; n < 4; ++n)
                    acc[m][n] = __builtin_amdgcn_mfma_f32_16x16x32_f16(
                        af[m], bf[n], acc[m][n], 0, 0, 0);
        }
        __syncthreads();
    }

    // epilogue: s = tanh(acc + ph[b][u]); partial_logit[row] = sum_u s*V[u]
    int bidx = mt >> 4;
    const float* phb = ph + bidx * U_;
    float Vv[4], phv[4];
    #pragma unroll
    for (int n = 0; n < 4; ++n) {
        int u = nt * BN + wc * 64 + n * 16 + lrow;
        Vv[n] = V[u];
        phv[n] = phb[u];
    }
    #pragma unroll
    for (int m = 0; m < 4; ++m) {
        #pragma unroll
        for (int r = 0; r < 4; ++r) {
            float p = 0.f;
            #pragma unroll
            for (int n = 0; n < 4; ++n) {
                float s = fast_tanh(acc[m][n][r] + phv[n]);
                p = fmaf(s, Vv[n], p);
            }
            #pragma unroll
            for (int off = 1; off < 16; off <<= 1)
                p += __shfl_xor(p, off, 64);
            if (lrow == 0) {
                int row = wr * 64 + m * 16 + ((lane >> 4) << 2) + r;
                lbuf[wc][row] = p;
            }
        }
    }
    __syncthreads();
    if (tid < BM) {
        float v = lbuf[0][tid] + lbuf[1][tid];
        part[(size_t)nt * M_ + mt * BM + tid] = v;
    }
}

// ---------------- fallback GEMM (f32 A, reg-staged) — round-1 proven ----------------
__global__ __launch_bounds__(256, 2)
void gemm_logits_f32_kernel(const float* __restrict__ A,
                            const _Float16* __restrict__ Bt,
                            const float* __restrict__ ph,
                            const float* __restrict__ V,
                            float* __restrict__ part)
{
    __shared__ _Float16 As[BM * BK];
    __shared__ _Float16 Bs[BN * BK];
    __shared__ float lbuf[2][BM];

    int mt, nt;
    block_map(blockIdx.x, mt, nt);
    int tid = threadIdx.x;
    int lane = tid & 63, wid = tid >> 6;
    int wr = wid >> 1, wc = wid & 1;
    int lrow = lane & 15, lk = (lane >> 4) << 3;

    const float* Ag = A + (size_t)(mt * BM) * D_;
    const _Float16* Bg = Bt + (size_t)(nt * BN) * D_;

    f32x4 acc[4][4] = {};
    int srow = tid >> 3, soct = tid & 7;

    for (int k0 = 0; k0 < D_; k0 += BK) {
        #pragma unroll
        for (int p = 0; p < 4; ++p) {
            int row = srow + p * 32;
            const float* g = Ag + (size_t)row * D_ + k0 + soct * 8;
            f32x4 v0 = *(const f32x4*)g;
            f32x4 v1 = *(const f32x4*)(g + 4);
            f16x8 h;
            h[0] = (_Float16)v0[0]; h[1] = (_Float16)v0[1];
            h[2] = (_Float16)v0[2]; h[3] = (_Float16)v0[3];
            h[4] = (_Float16)v1[0]; h[5] = (_Float16)v1[1];
            h[6] = (_Float16)v1[2]; h[7] = (_Float16)v1[3];
            int unit = soct ^ (row & 7);
            *(f16x8*)&As[row * BK + unit * 8] = h;
        }
        #pragma unroll
        for (int p = 0; p < 4; ++p) {
            int row = srow + p * 32;
            f16x8 h = *(const f16x8*)(Bg + (size_t)row * D_ + k0 + soct * 8);
            int unit = soct ^ (row & 7);
            *(f16x8*)&Bs[row * BK + unit * 8] = h;
        }
        __syncthreads();
        #pragma unroll
        for (int kk = 0; kk < BK; kk += 32) {
            int k = kk + lk;
            f16x8 af[4], bf[4];
            #pragma unroll
            for (int m = 0; m < 4; ++m) {
                int row = wr * 64 + m * 16 + lrow;
                af[m] = *(const f16x8*)&As[row * BK + (((k >> 3) ^ (row & 7)) << 3)];
            }
            #pragma unroll
            for (int n = 0; n < 4; ++n) {
                int row = wc * 64 + n * 16 + lrow;
                bf[n] = *(const f16x8*)&Bs[row * BK + (((k >> 3) ^ (row & 7)) << 3)];
            }
            #pragma unroll
            for (int m = 0; m < 4; ++m)
                #pragma unroll
                for (int n = 0; n < 4; ++n)
                    acc[m][n] = __builtin_amdgcn_mfma_f32_16x16x32_f16(
                        af[m], bf[n], acc[m][n], 0, 0, 0);
        }
        __syncthreads();
    }

    int bidx = mt >> 4;
    const float* phb = ph + bidx * U_;
    float Vv[4], phv[4];
    #pragma unroll
    for (int n = 0; n < 4; ++n) {
        int u = nt * BN + wc * 64 + n * 16 + lrow;
        Vv[n] = V[u];
        phv[n] = phb[u];
    }
    #pragma unroll
    for (int m = 0; m < 4; ++m) {
        #pragma unroll
        for (int r = 0; r < 4; ++r) {
            float p = 0.f;
            #pragma unroll
            for (int n = 0; n < 4; ++n) {
                float s = fast_tanh(acc[m][n][r] + phv[n]);
                p = fmaf(s, Vv[n], p);
            }
            #pragma unroll
            for (int off = 1; off < 16; off <<= 1)
                p += __shfl_xor(p, off, 64);
            if (lrow == 0) {
                int row = wr * 64 + m * 16 + ((lane >> 4) << 2) + r;
                lbuf[wc][row] = p;
            }
        }
    }
    __syncthreads();
    if (tid < BM) {
        float v = lbuf[0][tid] + lbuf[1][tid];
        part[(size_t)nt * M_ + mt * BM + tid] = v;
    }
}

// ---------------- softmax over T per batch ----------------
__global__ void softmax_kernel(const float* __restrict__ part,
                               float* __restrict__ wout) {
    int b = blockIdx.x;
    int tid = threadIdx.x;
    __shared__ float red[8];
    float l[8];
    #pragma unroll
    for (int j = 0; j < 8; ++j) {
        int t = tid + j * 256;
        float s = 0.f;
        #pragma unroll
        for (int p = 0; p < NT_; ++p)
            s += part[(size_t)p * M_ + b * T_ + t];
        l[j] = s;
    }
    float mx = l[0];
    #pragma unroll
    for (int j = 1; j < 8; ++j) mx = fmaxf(mx, l[j]);
    #pragma unroll
    for (int off = 1; off < 64; off <<= 1) mx = fmaxf(mx, __shfl_xor(mx, off, 64));
    int wv = tid >> 6;
    if ((tid & 63) == 0) red[wv] = mx;
    __syncthreads();
    mx = fmaxf(fmaxf(red[0], red[1]), fmaxf(red[2], red[3]));
    float e[8];
    float sum = 0.f;
    #pragma unroll
    for (int j = 0; j < 8; ++j) { e[j] = __expf(l[j] - mx); sum += e[j]; }
    #pragma unroll
    for (int off = 1; off < 64; off <<= 1) sum += __shfl_xor(sum, off, 64);
    if ((tid & 63) == 0) red[4 + wv] = sum;
    __syncthreads();
    sum = red[4] + red[5] + red[6] + red[7];
    float inv = 1.f / sum;
    #pragma unroll
    for (int j = 0; j < 8; ++j)
        wout[b * T_ + tid + j * 256] = e[j] * inv;
}

// ---------------- context = sum_t w_t * features[b,t,:] ----------------
#define TCH 128
__global__ void context_partial_f16_kernel(const _Float16* __restrict__ feats,
                                           const float* __restrict__ w,
                                           float* __restrict__ cpart) {
    int b = blockIdx.x, tc = blockIdx.y, tid = threadIdx.x;
    f32x4 acc = {0.f, 0.f, 0.f, 0.f};
    const _Float16* f = feats + ((size_t)b * T_ + tc * TCH) * D_ + tid * 4;
    const float* wp = w + b * T_ + tc * TCH;
    #pragma unroll 4
    for (int t = 0; t < TCH; ++t) {
        float wt = wp[t];
        f16x4 fv = *(const f16x4*)(f + (size_t)t * D_);
        acc[0] = fmaf(wt, (float)fv[0], acc[0]);
        acc[1] = fmaf(wt, (float)fv[1], acc[1]);
        acc[2] = fmaf(wt, (float)fv[2], acc[2]);
        acc[3] = fmaf(wt, (float)fv[3], acc[3]);
    }
    *(f32x4*)&cpart[((size_t)tc * B_ + b) * D_ + tid * 4] = acc;
}

__global__ void context_partial_f32_kernel(const float* __restrict__ feats,
                                           const float* __restrict__ w,
                                           float* __restrict__ cpart) {
    int b = blockIdx.x, tc = blockIdx.y, tid = threadIdx.x;
    f32x4 acc = {0.f, 0.f, 0.f, 0.f};
    const float* f = feats + ((size_t)b * T_ + tc * TCH) * D_ + tid * 4;
    const float* wp = w + b * T_ + tc * TCH;
    for (int t = 0; t < TCH; ++t) {
        float wt = wp[t];
        f32x4 fv = *(const f32x4*)(f + (size_t)t * D_);
        acc[0] = fmaf(wt, fv[0], acc[0]);
        acc[1] = fmaf(wt, fv[1], acc[1]);
        acc[2] = fmaf(wt, fv[2], acc[2]);
        acc[3] = fmaf(wt, fv[3], acc[3]);
    }
    *(f32x4*)&cpart[((size_t)tc * B_ + b) * D_ + tid * 4] = acc;
}

__global__ void context_reduce_kernel(const float* __restrict__ cpart,
                                      float* __restrict__ out) {
    int i = blockIdx.x * 256 + threadIdx.x;
    float s = 0.f;
    #pragma unroll
    for (int tc = 0; tc < 16; ++tc)
        s += cpart[(size_t)tc * (B_ * D_) + i];
    out[i] = s;
}

extern "C" void kernel_launch(void* const* d_in, const int* in_sizes, int n_in,
                              void* d_out, int out_size, void* d_ws, size_t ws_size,
                              hipStream_t stream) {
    const float* features = (const float*)d_in[0];
    const float* hidden   = (const float*)d_in[1];
    const float* W1       = (const float*)d_in[2];
    const float* b1       = (const float*)d_in[3];
    const float* W2       = (const float*)d_in[4];
    const float* b2       = (const float*)d_in[5];
    const float* V        = (const float*)d_in[6];
    // bV drops out of softmax (shift-invariant).

    float* ctx_out = (float*)d_out;            // [B,D]
    float* w_out   = ctx_out + B_ * D_;        // [B,T,1]

    char* ws = (char*)d_ws;
    _Float16* W1t  = (_Float16*)ws;                               // 2 MB
    float* ph      = (float*)(ws + (2 << 20));                    // 128 KB
    float* part    = (float*)(ws + (2 << 20) + (1 << 17));        // 2 MB
    float* cpart   = (float*)(ws + (4 << 20) + (1 << 17));        // 2 MB
    _Float16* featH = (_Float16*)(ws + (8 << 20));                // 128 MB
    size_t need = (size_t)(8 << 20) + (size_t)M_ * D_ * sizeof(_Float16);
    bool use_f16 = ws_size >= need;

    transpose_cast_kernel<<<dim3(4, 16), 256, 0, stream>>>(W1, W1t);
    proj_h_kernel<<<dim3(4, 32), 256, 0, stream>>>(hidden, W2, b1, b2, ph);

    if (use_f16) {
        precast_kernel<<<2048, 256, 0, stream>>>(features, featH);
        gemm_logits_f16_kernel<<<(M_ / BM) * (U_ / BN), 256, 0, stream>>>(
            featH, W1t, ph, V, part);
    } else {
        gemm_logits_f32_kernel<<<(M_ / BM) * (U_ / BN), 256, 0, stream>>>(
            features, W1t, ph, V, part);
    }

    softmax_kernel<<<B_, 256, 0, stream>>>(part, w_out);

    if (use_f16) {
        context_partial_f16_kernel<<<dim3(B_, 16), 256, 0, stream>>>(featH, w_out, cpart);
    } else {
        context_partial_f32_kernel<<<dim3(B_, 16), 256, 0, stream>>>(features, w_out, cpart);
    }
    context_reduce_kernel<<<(B_ * D_) / 256, 256, 0, stream>>>(cpart, ctx_out);
}

// Round 3
// 318.366 us; speedup vs baseline: 1.6407x; 1.0871x over previous
//
#include <hip/hip_runtime.h>
#include <hip/hip_bf16.h>
#include <hip/hip_fp16.h>

#define B_ 32
#define T_ 2048
#define D_ 1024
#define U_ 1024
#define M_ (B_ * T_)   // 65536
#define NT_ 4          // U_/256 partial-logit slabs

typedef _Float16 f16x8 __attribute__((ext_vector_type(8)));
typedef _Float16 f16x4 __attribute__((ext_vector_type(4)));
typedef float f32x4 __attribute__((ext_vector_type(4)));

__device__ __forceinline__ float fast_tanh(float x) {
    float xc = fminf(fmaxf(x, -10.f), 10.f);
    float e = __expf(2.f * xc);
    return 1.f - 2.f / (e + 1.f);
}

__device__ __forceinline__ void load_lds16(const void* g, void* l) {
    __builtin_amdgcn_global_load_lds(
        (const __attribute__((address_space(1))) void*)g,
        (__attribute__((address_space(3))) void*)l, 16, 0, 0);
}

// ---------------- features f32 -> f16 (linear copy) ----------------
__global__ void precast_kernel(const float* __restrict__ in,
                               _Float16* __restrict__ out) {
    size_t i = (size_t)blockIdx.x * 256 + threadIdx.x;
    const size_t stride = (size_t)2048 * 256;
    const size_t n8 = (size_t)M_ * D_ / 8;
    for (size_t j = i; j < n8; j += stride) {
        f32x4 a = *(const f32x4*)(in + j * 8);
        f32x4 b = *(const f32x4*)(in + j * 8 + 4);
        f16x8 h;
        h[0] = (_Float16)a[0]; h[1] = (_Float16)a[1];
        h[2] = (_Float16)a[2]; h[3] = (_Float16)a[3];
        h[4] = (_Float16)b[0]; h[5] = (_Float16)b[1];
        h[6] = (_Float16)b[2]; h[7] = (_Float16)b[3];
        *(f16x8*)(out + j * 8) = h;
    }
}

// ---------------- W1 [D][U] f32 -> W1t [U][D] f16 ----------------
__global__ void transpose_cast_kernel(const float* __restrict__ W1,
                                      _Float16* __restrict__ W1t) {
    int u = blockIdx.x * 256 + threadIdx.x;   // grid.x = 4
    int d0 = blockIdx.y * 64;                 // grid.y = 16
    for (int j8 = 0; j8 < 8; ++j8) {
        f16x8 h;
        #pragma unroll
        for (int j = 0; j < 8; ++j)
            h[j] = (_Float16)W1[(size_t)(d0 + j8 * 8 + j) * U_ + u];
        *(f16x8*)&W1t[(size_t)u * D_ + d0 + j8 * 8] = h;
    }
}

// ---------------- proj_h: W2 read once, d-split partials ----------------
__global__ void proj_h_partial_kernel(const float* __restrict__ hidden,
                                      const float* __restrict__ W2,
                                      float* __restrict__ pph) {
    int u = blockIdx.x * 256 + threadIdx.x;   // grid.x = 4
    int c = blockIdx.y;                       // grid.y = 8 (d-chunks of 128)
    __shared__ float hb[32][128];
    for (int i = threadIdx.x; i < 32 * 128; i += 256)
        hb[i >> 7][i & 127] = hidden[(i >> 7) * D_ + c * 128 + (i & 127)];
    __syncthreads();
    float acc[32] = {};
    for (int d = 0; d < 128; ++d) {
        float w = W2[(size_t)(c * 128 + d) * U_ + u];
        #pragma unroll
        for (int b = 0; b < 32; ++b) acc[b] = fmaf(hb[b][d], w, acc[b]);
    }
    #pragma unroll
    for (int b = 0; b < 32; ++b)
        pph[((size_t)c * 32 + b) * U_ + u] = acc[b];
}

__global__ void proj_h_combine_kernel(const float* __restrict__ pph,
                                      const float* __restrict__ b1,
                                      const float* __restrict__ b2,
                                      float* __restrict__ ph) {
    int u = blockIdx.x * 256 + threadIdx.x;   // grid 4
    float bias = b1[u] + b2[u];
    for (int b = 0; b < 32; ++b) {
        float s = bias;
        #pragma unroll
        for (int c = 0; c < 8; ++c) s += pph[((size_t)c * 32 + b) * U_ + u];
        ph[b * U_ + u] = s;
    }
}

// ============ fused 256x256 8-phase GEMM + tanh + dot(V) ============
// BM=BN=256, BK=64 (2 khalves of 32), 512 threads = 8 waves (2Mx4N),
// LDS 128KB: [buf][khalf]{ A 256x32, B 256x32 } f16, dbuf.
// Swizzle: LDS[row][unit] (16B units, 4/row) holds global chunk unit^((row>>1)&3).

#define VM4 asm volatile("s_waitcnt vmcnt(4)" ::: "memory");
#define VM0 asm volatile("s_waitcnt vmcnt(0)" ::: "memory");

#define STAGE_A(bb, kh, kof) \
    load_lds16(pA + (kof) + (kh) * 64, sb + (bb) * 65536 + (kh) * 16384 + tid * 16); \
    load_lds16(pA + (size_t)128 * D_ * 2 + (kof) + (kh) * 64, \
               sb + (bb) * 65536 + (kh) * 16384 + 8192 + tid * 16);
#define STAGE_B(bb, kh, kof) \
    load_lds16(pB + (kof) + (kh) * 64, sb + (bb) * 65536 + 32768 + (kh) * 16384 + tid * 16); \
    load_lds16(pB + (size_t)128 * D_ * 2 + (kof) + (kh) * 64, \
               sb + (bb) * 65536 + 32768 + (kh) * 16384 + 8192 + tid * 16);

#define PH(curv, kh, mh, STG, WAITV) do { \
    const char* base_ = sb + (curv) * 65536 + (kh) * 16384; \
    if ((mh) == 0) { \
        _Pragma("unroll") \
        for (int n_ = 0; n_ < 4; ++n_) \
            bf[n_] = *(const f16x8*)(base_ + 32768 + wc * 4096 + n_ * 1024 + laneOff); \
    } \
    _Pragma("unroll") \
    for (int m_ = 0; m_ < 4; ++m_) \
        af[m_] = *(const f16x8*)(base_ + wr * 8192 + (mh) * 4096 + m_ * 1024 + laneOff); \
    STG \
    __builtin_amdgcn_sched_barrier(0); \
    WAITV \
    __builtin_amdgcn_sched_barrier(0); \
    __builtin_amdgcn_s_barrier(); \
    asm volatile("s_waitcnt lgkmcnt(0)" ::: "memory"); \
    __builtin_amdgcn_sched_barrier(0); \
    __builtin_amdgcn_s_setprio(1); \
    _Pragma("unroll") \
    for (int m_ = 0; m_ < 4; ++m_) { \
        _Pragma("unroll") \
        for (int n_ = 0; n_ < 4; ++n_) \
            acc[(mh) * 4 + m_][n_] = __builtin_amdgcn_mfma_f32_16x16x32_f16( \
                af[m_], bf[n_], acc[(mh) * 4 + m_][n_], 0, 0, 0); \
    } \
    __builtin_amdgcn_s_setprio(0); \
    __builtin_amdgcn_sched_barrier(0); \
    __builtin_amdgcn_s_barrier(); \
    __builtin_amdgcn_sched_barrier(0); \
} while (0)

__global__ __launch_bounds__(512, 2)
void gemm_logits_8ph_kernel(const _Float16* __restrict__ A,   // featH [M][D]
                            const _Float16* __restrict__ Bt,  // W1t [U][D]
                            const float* __restrict__ ph,
                            const float* __restrict__ V,
                            float* __restrict__ part)         // [NT_][M]
{
    __shared__ __align__(16) char smem_raw[131072];
    char* sb = smem_raw;

    // XCD-chunked mapping: 1024 blocks, xcd owns contiguous 32 mt x 4 nt.
    int bid = blockIdx.x;
    int xcd = bid & 7, local = bid >> 3;
    int mt = xcd * 32 + (local >> 2);   // 0..255
    int nt = local & 3;                 // 0..3

    int tid = threadIdx.x;
    int l = tid & 63, wid = tid >> 6;
    int wr = wid >> 2, wc = wid & 3;    // 2M x 4N waves
    int lrow = l & 15;

    const _Float16* Ag = A + (size_t)mt * 256 * D_;
    const _Float16* Bg = Bt + (size_t)nt * 256 * D_;

    // staging addresses (pre-swizzled source): thread t covers rows t>>2 and t>>2+128
    int srow = tid >> 2;
    int chunk = (tid & 3) ^ ((srow >> 1) & 3);
    size_t rb = (size_t)srow * (D_ * 2) + (size_t)chunk * 16;
    const char* pA = (const char*)Ag + rb;
    const char* pB = (const char*)Bg + rb;

    // ds_read lane offset: row = <mult16> + lrow, unit = (l>>4) ^ ((lrow>>1)&3)
    int laneOff = lrow * 64 + (((l >> 4) ^ ((lrow >> 1) & 3)) << 4);

    f32x4 acc[8][4] = {};
    f16x8 af[4], bf[4];

    // prologue: stage tile0 fully (A0,B0,A1,B1), keep k1 halves in flight
    STAGE_A(0, 0, 0)
    STAGE_B(0, 0, 0)
    STAGE_A(0, 1, 0)
    STAGE_B(0, 1, 0)
    VM4
    __builtin_amdgcn_s_barrier();
    __builtin_amdgcn_sched_barrier(0);

    #pragma unroll 1
    for (int t = 0; t < 15; ++t) {
        int cur = t & 1, nxt = cur ^ 1;
        int kof = (t + 1) * 128;   // bytes into the k dimension
        PH(cur, 0, 0, STAGE_A(nxt, 0, kof), );
        PH(cur, 0, 1, STAGE_B(nxt, 0, kof), VM4);
        PH(cur, 1, 0, STAGE_A(nxt, 1, kof), );
        PH(cur, 1, 1, STAGE_B(nxt, 1, kof), VM4);
    }
    // tail tile 15 (cur=1), no staging
    PH(1, 0, 0, , );
    PH(1, 0, 1, , VM0);
    PH(1, 1, 0, , );
    PH(1, 1, 1, , );

    // ---- fused epilogue: s=tanh(acc+ph), partial = sum_u s*V ----
    int bidx = mt >> 3;               // batch (8 m-tiles per batch)
    const float* phb = ph + bidx * U_;
    float Vv[4], phv[4];
    #pragma unroll
    for (int n = 0; n < 4; ++n) {
        int u = nt * 256 + wc * 64 + n * 16 + lrow;
        Vv[n] = V[u];
        phv[n] = phb[u];
    }
    float* lbuf = (float*)smem_raw;   // [4][256] (wc-major); safe after final barrier
    #pragma unroll
    for (int mh = 0; mh < 2; ++mh) {
        #pragma unroll
        for (int m = 0; m < 4; ++m) {
            #pragma unroll
            for (int r = 0; r < 4; ++r) {
                float p = 0.f;
                #pragma unroll
                for (int n = 0; n < 4; ++n) {
                    float s = fast_tanh(acc[mh * 4 + m][n][r] + phv[n]);
                    p = fmaf(s, Vv[n], p);
                }
                #pragma unroll
                for (int off = 1; off < 16; off <<= 1)
                    p += __shfl_xor(p, off, 64);
                if (lrow == 0) {
                    int row = wr * 128 + mh * 64 + m * 16 + ((l >> 4) << 2) + r;
                    lbuf[wc * 256 + row] = p;
                }
            }
        }
    }
    __syncthreads();
    if (tid < 256) {
        float v = lbuf[tid] + lbuf[256 + tid] + lbuf[512 + tid] + lbuf[768 + tid];
        part[(size_t)nt * M_ + mt * 256 + tid] = v;
    }
}

// ---------------- softmax over T per batch ----------------
__global__ void softmax_kernel(const float* __restrict__ part,
                               float* __restrict__ wout) {
    int b = blockIdx.x;
    int tid = threadIdx.x;
    __shared__ float red[8];
    float lg[8];
    #pragma unroll
    for (int j = 0; j < 8; ++j) {
        int t = tid + j * 256;
        float s = 0.f;
        #pragma unroll
        for (int p = 0; p < NT_; ++p)
            s += part[(size_t)p * M_ + b * T_ + t];
        lg[j] = s;
    }
    float mx = lg[0];
    #pragma unroll
    for (int j = 1; j < 8; ++j) mx = fmaxf(mx, lg[j]);
    #pragma unroll
    for (int off = 1; off < 64; off <<= 1) mx = fmaxf(mx, __shfl_xor(mx, off, 64));
    int wv = tid >> 6;
    if ((tid & 63) == 0) red[wv] = mx;
    __syncthreads();
    mx = fmaxf(fmaxf(red[0], red[1]), fmaxf(red[2], red[3]));
    float e[8];
    float sum = 0.f;
    #pragma unroll
    for (int j = 0; j < 8; ++j) { e[j] = __expf(lg[j] - mx); sum += e[j]; }
    #pragma unroll
    for (int off = 1; off < 64; off <<= 1) sum += __shfl_xor(sum, off, 64);
    if ((tid & 63) == 0) red[4 + wv] = sum;
    __syncthreads();
    sum = red[4] + red[5] + red[6] + red[7];
    float inv = 1.f / sum;
    #pragma unroll
    for (int j = 0; j < 8; ++j)
        wout[b * T_ + tid + j * 256] = e[j] * inv;
}

// ---------------- context = sum_t w_t * features[b,t,:] ----------------
#define TCH 128
__global__ void context_partial_f16_kernel(const _Float16* __restrict__ feats,
                                           const float* __restrict__ w,
                                           float* __restrict__ cpart) {
    int b = blockIdx.x, tc = blockIdx.y, tid = threadIdx.x;
    f32x4 acc = {0.f, 0.f, 0.f, 0.f};
    const _Float16* f = feats + ((size_t)b * T_ + tc * TCH) * D_ + tid * 4;
    const float* wp = w + b * T_ + tc * TCH;
    #pragma unroll 4
    for (int t = 0; t < TCH; ++t) {
        float wt = wp[t];
        f16x4 fv = *(const f16x4*)(f + (size_t)t * D_);
        acc[0] = fmaf(wt, (float)fv[0], acc[0]);
        acc[1] = fmaf(wt, (float)fv[1], acc[1]);
        acc[2] = fmaf(wt, (float)fv[2], acc[2]);
        acc[3] = fmaf(wt, (float)fv[3], acc[3]);
    }
    *(f32x4*)&cpart[((size_t)tc * B_ + b) * D_ + tid * 4] = acc;
}

__global__ void context_reduce_kernel(const float* __restrict__ cpart,
                                      float* __restrict__ out) {
    int i = blockIdx.x * 256 + threadIdx.x;
    float s = 0.f;
    #pragma unroll
    for (int tc = 0; tc < 16; ++tc)
        s += cpart[(size_t)tc * (B_ * D_) + i];
    out[i] = s;
}

extern "C" void kernel_launch(void* const* d_in, const int* in_sizes, int n_in,
                              void* d_out, int out_size, void* d_ws, size_t ws_size,
                              hipStream_t stream) {
    const float* features = (const float*)d_in[0];
    const float* hidden   = (const float*)d_in[1];
    const float* W1       = (const float*)d_in[2];
    const float* b1       = (const float*)d_in[3];
    const float* W2       = (const float*)d_in[4];
    const float* b2       = (const float*)d_in[5];
    const float* V        = (const float*)d_in[6];
    // bV drops out of softmax (shift-invariant).

    float* ctx_out = (float*)d_out;            // [B,D]
    float* w_out   = ctx_out + B_ * D_;        // [B,T,1]

    char* ws = (char*)d_ws;
    _Float16* W1t  = (_Float16*)ws;                     // 2 MB @ 0
    float* ph      = (float*)(ws + (size_t)(2 << 20));  // 128 KB @ 2M
    float* pph     = (float*)(ws + (size_t)(3 << 20));  // 1 MB  @ 3M
    float* part    = (float*)(ws + (size_t)(4 << 20));  // 1 MB  @ 4M (NT_=4)
    float* cpart   = (float*)(ws + (size_t)(6 << 20));  // 2 MB  @ 6M
    _Float16* featH = (_Float16*)(ws + (size_t)(8 << 20)); // 128 MB @ 8M

    transpose_cast_kernel<<<dim3(4, 16), 256, 0, stream>>>(W1, W1t);
    proj_h_partial_kernel<<<dim3(4, 8), 256, 0, stream>>>(hidden, W2, pph);
    proj_h_combine_kernel<<<4, 256, 0, stream>>>(pph, b1, b2, ph);
    precast_kernel<<<2048, 256, 0, stream>>>(features, featH);

    gemm_logits_8ph_kernel<<<(M_ / 256) * (U_ / 256), 512, 0, stream>>>(
        featH, W1t, ph, V, part);

    softmax_kernel<<<B_, 256, 0, stream>>>(part, w_out);
    context_partial_f16_kernel<<<dim3(B_, 16), 256, 0, stream>>>(featH, w_out, cpart);
    context_reduce_kernel<<<(B_ * D_) / 256, 256, 0, stream>>>(cpart, ctx_out);
}

// Round 4
// 297.072 us; speedup vs baseline: 1.7583x; 1.0717x over previous
//
#include <hip/hip_runtime.h>
#include <hip/hip_bf16.h>
#include <hip/hip_fp16.h>

#define B_ 32
#define T_ 2048
#define D_ 1024
#define U_ 1024
#define M_ (B_ * T_)   // 65536
#define NT_ 4          // U_/256 partial-logit slabs

typedef _Float16 f16x8 __attribute__((ext_vector_type(8)));
typedef float f32x4 __attribute__((ext_vector_type(4)));

__device__ __forceinline__ float fast_tanh(float x) {
    float xc = fminf(fmaxf(x, -10.f), 10.f);
    float e = __expf(2.f * xc);
    return 1.f - 2.f / (e + 1.f);
}

__device__ __forceinline__ void load_lds16(const void* g, void* l) {
    __builtin_amdgcn_global_load_lds(
        (const __attribute__((address_space(1))) void*)g,
        (__attribute__((address_space(3))) void*)l, 16, 0, 0);
}

// ---------------- W1 [D][U] f32 -> W1t [U][D] f16 ----------------
__global__ void transpose_cast_kernel(const float* __restrict__ W1,
                                      _Float16* __restrict__ W1t) {
    int u = blockIdx.x * 256 + threadIdx.x;   // grid.x = 4
    int d0 = blockIdx.y * 64;                 // grid.y = 16
    for (int j8 = 0; j8 < 8; ++j8) {
        f16x8 h;
        #pragma unroll
        for (int j = 0; j < 8; ++j)
            h[j] = (_Float16)W1[(size_t)(d0 + j8 * 8 + j) * U_ + u];
        *(f16x8*)&W1t[(size_t)u * D_ + d0 + j8 * 8] = h;
    }
}

// ---------------- proj_h: W2 read once, d-split partials ----------------
__global__ void proj_h_partial_kernel(const float* __restrict__ hidden,
                                      const float* __restrict__ W2,
                                      float* __restrict__ pph) {
    int u = blockIdx.x * 256 + threadIdx.x;   // grid.x = 4
    int c = blockIdx.y;                       // grid.y = 8
    __shared__ float hb[32][128];
    for (int i = threadIdx.x; i < 32 * 128; i += 256)
        hb[i >> 7][i & 127] = hidden[(i >> 7) * D_ + c * 128 + (i & 127)];
    __syncthreads();
    float acc[32] = {};
    for (int d = 0; d < 128; ++d) {
        float w = W2[(size_t)(c * 128 + d) * U_ + u];
        #pragma unroll
        for (int b = 0; b < 32; ++b) acc[b] = fmaf(hb[b][d], w, acc[b]);
    }
    #pragma unroll
    for (int b = 0; b < 32; ++b)
        pph[((size_t)c * 32 + b) * U_ + u] = acc[b];
}

__global__ void proj_h_combine_kernel(const float* __restrict__ pph,
                                      const float* __restrict__ b1,
                                      const float* __restrict__ b2,
                                      float* __restrict__ ph) {
    int u = blockIdx.x * 256 + threadIdx.x;
    float bias = b1[u] + b2[u];
    for (int b = 0; b < 32; ++b) {
        float s = bias;
        #pragma unroll
        for (int c = 0; c < 8; ++c) s += pph[((size_t)c * 32 + b) * U_ + u];
        ph[b * U_ + u] = s;
    }
}

// ============ fused 256x256 GEMM (1 barrier/K-tile) + tanh + dot(V) ============
// BM=BN=256, BK=64, 512 thr = 8 waves (2M x 4N), wave tile 128x64.
// LDS 128KB: buf{0,1} x [ A 256x64 f16 (32KB) | B 256x64 f16 (32KB) ].
// 8-unit XOR swizzle: physical 16B-unit = logical ^ (row&7), both sides.
// A: f32 HBM -> regs -> cvt f16 -> swizzled ds_write (fused precast).
// B: f16, global_load_lds linear dest + inverse-swizzled source.

#define ISSUE_A(koff) do { \
    const float* a0_ = pA0 + (koff); \
    const float* a1_ = pA1 + (koff); \
    araw0 = *(const f32x4*)(a0_);      araw1 = *(const f32x4*)(a0_ + 4); \
    araw2 = *(const f32x4*)(a0_ + 8);  araw3 = *(const f32x4*)(a0_ + 12); \
    araw4 = *(const f32x4*)(a1_);      araw5 = *(const f32x4*)(a1_ + 4); \
    araw6 = *(const f32x4*)(a1_ + 8);  araw7 = *(const f32x4*)(a1_ + 12); \
} while (0)

#define ISSUE_B(koffb, bufoff) do { \
    load_lds16(pB + 0 * 131072 + (koffb), smem + (bufoff) + 32768 + 0 * 8192 + tid * 16); \
    load_lds16(pB + 1 * 131072 + (koffb), smem + (bufoff) + 32768 + 1 * 8192 + tid * 16); \
    load_lds16(pB + 2 * 131072 + (koffb), smem + (bufoff) + 32768 + 2 * 8192 + tid * 16); \
    load_lds16(pB + 3 * 131072 + (koffb), smem + (bufoff) + 32768 + 3 * 8192 + tid * 16); \
} while (0)

#define WRITE_A(nbptr) do { \
    f16x8 h0_, h1_, h2_, h3_; \
    h0_[0]=(_Float16)araw0[0]; h0_[1]=(_Float16)araw0[1]; h0_[2]=(_Float16)araw0[2]; h0_[3]=(_Float16)araw0[3]; \
    h0_[4]=(_Float16)araw1[0]; h0_[5]=(_Float16)araw1[1]; h0_[6]=(_Float16)araw1[2]; h0_[7]=(_Float16)araw1[3]; \
    h1_[0]=(_Float16)araw2[0]; h1_[1]=(_Float16)araw2[1]; h1_[2]=(_Float16)araw2[2]; h1_[3]=(_Float16)araw2[3]; \
    h1_[4]=(_Float16)araw3[0]; h1_[5]=(_Float16)araw3[1]; h1_[6]=(_Float16)araw3[2]; h1_[7]=(_Float16)araw3[3]; \
    h2_[0]=(_Float16)araw4[0]; h2_[1]=(_Float16)araw4[1]; h2_[2]=(_Float16)araw4[2]; h2_[3]=(_Float16)araw4[3]; \
    h2_[4]=(_Float16)araw5[0]; h2_[5]=(_Float16)araw5[1]; h2_[6]=(_Float16)araw5[2]; h2_[7]=(_Float16)araw5[3]; \
    h3_[0]=(_Float16)araw6[0]; h3_[1]=(_Float16)araw6[1]; h3_[2]=(_Float16)araw6[2]; h3_[3]=(_Float16)araw6[3]; \
    h3_[4]=(_Float16)araw7[0]; h3_[5]=(_Float16)araw7[1]; h3_[6]=(_Float16)araw7[2]; h3_[7]=(_Float16)araw7[3]; \
    *(f16x8*)((nbptr) + aw00) = h0_; \
    *(f16x8*)((nbptr) + aw01) = h1_; \
    *(f16x8*)((nbptr) + aw10) = h2_; \
    *(f16x8*)((nbptr) + aw11) = h3_; \
} while (0)

__global__ __launch_bounds__(512, 2)
void gemm_logits_v4_kernel(const float* __restrict__ A,      // features [M][D] f32
                           const _Float16* __restrict__ Bt,  // W1t [U][D] f16
                           const float* __restrict__ ph,
                           const float* __restrict__ V,
                           float* __restrict__ part)         // [NT_][M]
{
    __shared__ __align__(16) char smem[131072];

    // XCD-chunked mapping: 1024 blocks; xcd owns contiguous 32 mt x 4 nt.
    int bid = blockIdx.x;
    int xcd = bid & 7, local = bid >> 3;
    int mt = xcd * 32 + (local >> 2);   // 0..255
    int nt = local & 3;                 // 0..3

    int tid = threadIdx.x;
    int l = tid & 63, wid = tid >> 6;
    int wr = wid >> 2, wc = wid & 3;    // 2M x 4N waves
    int lrow = l & 15, lksl = l >> 4;   // 0..3

    const float* Ag = A + (size_t)mt * 256 * D_;
    const _Float16* Bg = Bt + (size_t)nt * 256 * D_;

    // A staging: thread covers rows (tid>>2) and (tid>>2)+128, 16 f32 each
    const float* pA0 = Ag + (size_t)(tid >> 2) * D_ + (tid & 3) * 16;
    const float* pA1 = pA0 + (size_t)128 * D_;
    // A LDS write byte offsets (8-unit swizzle; (r+128)&7 == r&7)
    int c2 = (tid & 3) * 2;
    int r0 = tid >> 2;
    int sw = r0 & 7;
    int aw00 = r0 * 128 + ((c2 ^ sw) << 4);
    int aw01 = r0 * 128 + (((c2 | 1) ^ sw) << 4);
    int aw10 = (r0 + 128) * 128 + ((c2 ^ sw) << 4);
    int aw11 = (r0 + 128) * 128 + (((c2 | 1) ^ sw) << 4);

    // B global_load_lds: linear dest, inverse-swizzled source
    int bchunk = (tid & 7) ^ ((tid >> 3) & 7);
    const char* pB = (const char*)Bg + (size_t)(tid >> 3) * 2048 + bchunk * 16;

    // ds_read bases
    int rowA = (wr * 128 + lrow) * 128;
    int rowB = 32768 + (wc * 64 + lrow) * 128;
    int sw7 = lrow & 7;

    f32x4 acc[8][4] = {};
    f32x4 araw0, araw1, araw2, araw3, araw4, araw5, araw6, araw7;

    // ---- prologue: stage tile 0 into buf0 ----
    ISSUE_A(0);
    ISSUE_B(0, 0);
    WRITE_A(smem);   // compiler inserts vmcnt for araw deps
    __builtin_amdgcn_sched_barrier(0);
    asm volatile("s_waitcnt vmcnt(0)" ::: "memory");
    asm volatile("s_waitcnt lgkmcnt(0)" ::: "memory");
    __builtin_amdgcn_sched_barrier(0);
    __builtin_amdgcn_s_barrier();
    __builtin_amdgcn_sched_barrier(0);

    #pragma unroll 1
    for (int t = 0; t < 16; ++t) {
        const char* bb = smem + (t & 1) * 65536;
        char* nb = smem + ((t & 1) ^ 1) * 65536;
        if (t < 15) {
            ISSUE_A((t + 1) * 64);
            ISSUE_B((t + 1) * 128, ((t & 1) ^ 1) * 65536);
        }
        __builtin_amdgcn_s_setprio(1);
        #pragma unroll
        for (int kh = 0; kh < 2; ++kh) {
            int us = (((kh << 2) | lksl) ^ sw7) << 4;
            f16x8 af[8], bf[4];
            #pragma unroll
            for (int n = 0; n < 4; ++n)
                bf[n] = *(const f16x8*)(bb + rowB + n * 2048 + us);
            #pragma unroll
            for (int m = 0; m < 8; ++m)
                af[m] = *(const f16x8*)(bb + rowA + m * 2048 + us);
            #pragma unroll
            for (int m = 0; m < 8; ++m)
                #pragma unroll
                for (int n = 0; n < 4; ++n)
                    acc[m][n] = __builtin_amdgcn_mfma_f32_16x16x32_f16(
                        af[m], bf[n], acc[m][n], 0, 0, 0);
        }
        __builtin_amdgcn_s_setprio(0);
        if (t < 15) {
            WRITE_A(nb);
            __builtin_amdgcn_sched_barrier(0);
            asm volatile("s_waitcnt vmcnt(0)" ::: "memory");
            asm volatile("s_waitcnt lgkmcnt(0)" ::: "memory");
            __builtin_amdgcn_sched_barrier(0);
            __builtin_amdgcn_s_barrier();
            __builtin_amdgcn_sched_barrier(0);
        }
    }

    // ---- fused epilogue: s = tanh(acc + ph), partial = sum_u s*V ----
    int bidx = mt >> 3;               // 8 m-tiles of 256 per batch
    const float* phb = ph + bidx * U_;
    float Vv[4], phv[4];
    #pragma unroll
    for (int n = 0; n < 4; ++n) {
        int u = nt * 256 + wc * 64 + n * 16 + lrow;
        Vv[n] = V[u];
        phv[n] = phb[u];
    }
    float* lbuf = (float*)smem;       // buf0 A region; tile15 read buf1 -> disjoint
    #pragma unroll
    for (int m = 0; m < 8; ++m) {
        #pragma unroll
        for (int r = 0; r < 4; ++r) {
            float p = 0.f;
            #pragma unroll
            for (int n = 0; n < 4; ++n) {
                float s = fast_tanh(acc[m][n][r] + phv[n]);
                p = fmaf(s, Vv[n], p);
            }
            #pragma unroll
            for (int off = 1; off < 16; off <<= 1)
                p += __shfl_xor(p, off, 64);
            if (lrow == 0) {
                int row = wr * 128 + m * 16 + ((l >> 4) << 2) + r;
                lbuf[wc * 256 + row] = p;
            }
        }
    }
    __syncthreads();
    if (tid < 256) {
        float v = lbuf[tid] + lbuf[256 + tid] + lbuf[512 + tid] + lbuf[768 + tid];
        part[(size_t)nt * M_ + mt * 256 + tid] = v;
    }
}

// ---------------- softmax over T per batch ----------------
__global__ void softmax_kernel(const float* __restrict__ part,
                               float* __restrict__ wout) {
    int b = blockIdx.x;
    int tid = threadIdx.x;
    __shared__ float red[8];
    float lg[8];
    #pragma unroll
    for (int j = 0; j < 8; ++j) {
        int t = tid + j * 256;
        float s = 0.f;
        #pragma unroll
        for (int p = 0; p < NT_; ++p)
            s += part[(size_t)p * M_ + b * T_ + t];
        lg[j] = s;
    }
    float mx = lg[0];
    #pragma unroll
    for (int j = 1; j < 8; ++j) mx = fmaxf(mx, lg[j]);
    #pragma unroll
    for (int off = 1; off < 64; off <<= 1) mx = fmaxf(mx, __shfl_xor(mx, off, 64));
    int wv = tid >> 6;
    if ((tid & 63) == 0) red[wv] = mx;
    __syncthreads();
    mx = fmaxf(fmaxf(red[0], red[1]), fmaxf(red[2], red[3]));
    float e[8];
    float sum = 0.f;
    #pragma unroll
    for (int j = 0; j < 8; ++j) { e[j] = __expf(lg[j] - mx); sum += e[j]; }
    #pragma unroll
    for (int off = 1; off < 64; off <<= 1) sum += __shfl_xor(sum, off, 64);
    if ((tid & 63) == 0) red[4 + wv] = sum;
    __syncthreads();
    sum = red[4] + red[5] + red[6] + red[7];
    float inv = 1.f / sum;
    #pragma unroll
    for (int j = 0; j < 8; ++j)
        wout[b * T_ + tid + j * 256] = e[j] * inv;
}

// ---------------- context = sum_t w_t * features[b,t,:] (f32) ----------------
#define TCH 128
__global__ void context_partial_kernel(const float* __restrict__ feats,
                                       const float* __restrict__ w,
                                       float* __restrict__ cpart) {
    int b = blockIdx.x, tc = blockIdx.y, tid = threadIdx.x;
    f32x4 acc = {0.f, 0.f, 0.f, 0.f};
    const float* f = feats + ((size_t)b * T_ + tc * TCH) * D_ + tid * 4;
    const float* wp = w + b * T_ + tc * TCH;
    for (int t = 0; t < TCH; ++t) {
        float wt = wp[t];
        f32x4 fv = *(const f32x4*)(f + (size_t)t * D_);
        acc[0] = fmaf(wt, fv[0], acc[0]);
        acc[1] = fmaf(wt, fv[1], acc[1]);
        acc[2] = fmaf(wt, fv[2], acc[2]);
        acc[3] = fmaf(wt, fv[3], acc[3]);
    }
    *(f32x4*)&cpart[((size_t)tc * B_ + b) * D_ + tid * 4] = acc;
}

__global__ void context_reduce_kernel(const float* __restrict__ cpart,
                                      float* __restrict__ out) {
    int i = blockIdx.x * 256 + threadIdx.x;
    float s = 0.f;
    #pragma unroll
    for (int tc = 0; tc < 16; ++tc)
        s += cpart[(size_t)tc * (B_ * D_) + i];
    out[i] = s;
}

extern "C" void kernel_launch(void* const* d_in, const int* in_sizes, int n_in,
                              void* d_out, int out_size, void* d_ws, size_t ws_size,
                              hipStream_t stream) {
    const float* features = (const float*)d_in[0];
    const float* hidden   = (const float*)d_in[1];
    const float* W1       = (const float*)d_in[2];
    const float* b1       = (const float*)d_in[3];
    const float* W2       = (const float*)d_in[4];
    const float* b2       = (const float*)d_in[5];
    const float* V        = (const float*)d_in[6];
    // bV drops out of softmax (shift-invariant).

    float* ctx_out = (float*)d_out;            // [B,D]
    float* w_out   = ctx_out + B_ * D_;        // [B,T,1]

    char* ws = (char*)d_ws;
    _Float16* W1t = (_Float16*)ws;                      // 2 MB @ 0
    float* ph     = (float*)(ws + (size_t)(2 << 20));   // 128 KB @ 2M
    float* pph    = (float*)(ws + (size_t)(3 << 20));   // 1 MB @ 3M
    float* part   = (float*)(ws + (size_t)(4 << 20));   // 1 MB @ 4M
    float* cpart  = (float*)(ws + (size_t)(6 << 20));   // 2 MB @ 6M

    transpose_cast_kernel<<<dim3(4, 16), 256, 0, stream>>>(W1, W1t);
    proj_h_partial_kernel<<<dim3(4, 8), 256, 0, stream>>>(hidden, W2, pph);
    proj_h_combine_kernel<<<4, 256, 0, stream>>>(pph, b1, b2, ph);

    gemm_logits_v4_kernel<<<(M_ / 256) * (U_ / 256), 512, 0, stream>>>(
        features, W1t, ph, V, part);

    softmax_kernel<<<B_, 256, 0, stream>>>(part, w_out);
    context_partial_kernel<<<dim3(B_, 16), 256, 0, stream>>>(features, w_out, cpart);
    context_reduce_kernel<<<(B_ * D_) / 256, 256, 0, stream>>>(cpart, ctx_out);
}